// Round 19
// baseline (482.986 us; speedup 1.0000x reference)
//
#include <hip/hip_runtime.h>
#include <hip/hip_bf16.h>

#define BATCH 2048
#define KD 1024
#define ND 1024
#define NLEAF 64
#define BM 256
#define BN 256
#define RT_BLOCKS 512
// 16 K-tiles of BK=64; single full-N GEMM (65536 cols)

typedef __attribute__((ext_vector_type(8))) short bf16x8;
typedef __attribute__((ext_vector_type(4))) float f32x4;
typedef __attribute__((ext_vector_type(8))) _Float16 f16x8;

// workspace layout (bytes)
#define WLB_OFF 0ULL                 // B (Wl) bf16 row-major, 128 MB
#define XB_OFF  134217728ULL         // A (x) bf16 row-major, 4 MB
#define RT_OFF  138412032ULL         // routing 512 KB
#define LG_OFF  138936320ULL         // logits fp16, 268 MB

__device__ __forceinline__ unsigned short f2bf(float f) {
  unsigned int u = __float_as_uint(f);
  u += 0x7fffu + ((u >> 16) & 1u);
  return (unsigned short)(u >> 16);
}

__device__ __forceinline__ void gload_lds16(const void* g, void* l) {
  __builtin_amdgcn_global_load_lds(
      (const __attribute__((address_space(1))) unsigned int*)g,
      (__attribute__((address_space(3))) unsigned int*)l, 16, 0, 0);
}

// ---- kernel 1: fused prep — blocks [0,512) routing (f32 exact), ----
// ---- blocks [512,2560) grid-stride f32->bf16 convert of Wl and x ----
__global__ void __launch_bounds__(256) prep_kernel(
    const float* __restrict__ Wl, const float* __restrict__ x,
    const float* __restrict__ Wd, const float* __restrict__ bd,
    unsigned short* __restrict__ wlb, unsigned short* __restrict__ xb,
    float* __restrict__ rt) {
  __shared__ float xs[4][KD];
  __shared__ float sdp[4][64];
  const int tid = threadIdx.x;

  if (blockIdx.x < RT_BLOCKS) {
    // ---------------- routing (identical body to proven routing_kernel) ----
    const int b0 = blockIdx.x * 4;
    const float4* xsrc = (const float4*)(x + (size_t)b0 * KD);
    float4* xdst = (float4*)&xs[0][0];
    for (int i = tid; i < KD; i += 256) xdst[i] = xsrc[i];
    __syncthreads();
    const int wv = tid >> 6, ln = tid & 63;
    const int b = b0 + wv;
    if (ln < 63) {
      const float4* wrow = (const float4*)(Wd + (size_t)ln * KD);
      const float4* xr = (const float4*)&xs[wv][0];
      float4 a = {0.f, 0.f, 0.f, 0.f};
      for (int k = 0; k < KD / 4; ++k) {
        float4 w = wrow[k], xv = xr[k];
        a.x += w.x * xv.x; a.y += w.y * xv.y; a.z += w.z * xv.z; a.w += w.w * xv.w;
      }
      float z = a.x + a.y + a.z + a.w + bd[ln];
      sdp[wv][ln] = 1.f / (1.f + __expf(-z));
    }
    __syncthreads();
    float prod = 1.f;
    int node = 0, index = ln;
    for (int d = 0; d < 6; ++d) {
      float pv = sdp[wv][node];
      prod *= (index & 1) ? (1.f - pv) : pv;
      node = node * 2 + 1 + (index & 1);
      index >>= 1;
    }
    rt[(size_t)b * NLEAF + ln] = prod;
    return;
  }

  // ---------------- convert (identical math to proven convert_kernel) ----
  const long long WL4 = 16777216LL;
  const long long X4  = 524288LL;
  long long i = (long long)(blockIdx.x - RT_BLOCKS) * 256 + tid;
  const long long stride = (long long)(gridDim.x - RT_BLOCKS) * 256;
  for (; i < WL4 + X4; i += stride) {
    float4 v;
    if (i < WL4) v = ((const float4*)Wl)[i];
    else         v = ((const float4*)x)[i - WL4];
    ushort4 o;
    o.x = f2bf(v.x); o.y = f2bf(v.y); o.z = f2bf(v.z); o.w = f2bf(v.w);
    if (i < WL4) ((ushort4*)wlb)[i] = o;
    else         ((ushort4*)xb)[i - WL4] = o;
  }
}

// ---- kernel 3: 256x256 bf16 GEMM, BK=64, 2x64KB slots, ONE barrier+vmcnt ----
// ---- per tile; 24 upfront ds_reads overlap into 64 MFMAs (round-14 best) ----
__global__ void __launch_bounds__(512, 2) gemm_kernel(
    const unsigned short* __restrict__ A, const unsigned short* __restrict__ B,
    const float* __restrict__ blg, _Float16* __restrict__ C, int ntile) {
  extern __shared__ char smem[];   // 2 slots x 64KB: {A 32K | B 32K}
  const int tid = threadIdx.x;
  const int w = tid >> 6, ln = tid & 63;
  const int wm = w >> 2, wn = w & 3;
  const int g = ln >> 4, r16 = ln & 15;
  const int bid = blockIdx.x;
  const int j = bid >> 3;                       // XCD-chunked swizzle
  const int bm = (j & 7) * BM;
  const int bn = (((j >> 3) << 3) + (bid & 7)) * BN;
  const long long ldc = (long long)ntile * 256;

  // staging: rows 128B (8 chunks of 16B); thread -> (row tid>>3 + p*64, chunk tid&7)
  const int sr = tid >> 3, sj = tid & 7;
  const int sjx = sj ^ (sr & 7);                // both-sides swizzle, source
  const unsigned short* gA = A + (size_t)(bm + sr) * KD + sjx * 8;
  const unsigned short* gB = B + (size_t)(bn + sr) * KD + sjx * 8;
  const int ldsw = w * 1024;                    // wave-uniform dest component

  auto STAGE = [&](int t) {       // tile t (64 K-elems) -> slot t&1
    char* base = smem + (t & 1) * 65536;
    const size_t ko = (size_t)t * 64;
#pragma unroll
    for (int p = 0; p < 4; ++p) {
      gload_lds16(gA + (size_t)(p * 64) * KD + ko, base + p * 8192 + ldsw);
      gload_lds16(gB + (size_t)(p * 64) * KD + ko, base + 32768 + p * 8192 + ldsw);
    }
  };

  // read offsets: LDS chunk c holds source chunk c^(row&7); kk1 chunk 4^g -> ^64
  int offA[8], offB[4];
#pragma unroll
  for (int mi = 0; mi < 8; ++mi) {
    const int row = wm * 128 + mi * 16 + r16;
    offA[mi] = row * 128 + ((g ^ (row & 7)) * 16);
  }
#pragma unroll
  for (int ni = 0; ni < 4; ++ni) {
    const int row = wn * 64 + ni * 16 + r16;
    offB[ni] = 32768 + row * 128 + ((g ^ (row & 7)) * 16);
  }

  f32x4 acc[8][4];
#pragma unroll
  for (int mi = 0; mi < 8; ++mi)
#pragma unroll
    for (int ni = 0; ni < 4; ++ni) acc[mi][ni] = (f32x4){0.f, 0.f, 0.f, 0.f};

  STAGE(0);

  for (int t = 0; t < 16; ++t) {
    asm volatile("s_waitcnt vmcnt(0)" ::: "memory");   // STAGE(t) landed
    asm volatile("s_barrier" ::: "memory");            // slot t readable CU-wide;
                                                       // certifies reads(t-1) done
    if (t + 1 < 16) STAGE(t + 1);                      // slot (t+1)&1: tile t-1 done
    const char* buf = smem + (t & 1) * 65536;
    bf16x8 a0[8], a1[8], b0r[4], b1r[4];
#pragma unroll
    for (int mi = 0; mi < 8; ++mi) {
      a0[mi] = *(const bf16x8*)(buf + offA[mi]);
      a1[mi] = *(const bf16x8*)(buf + (offA[mi] ^ 64));
    }
#pragma unroll
    for (int ni = 0; ni < 4; ++ni) {
      b0r[ni] = *(const bf16x8*)(buf + offB[ni]);
      b1r[ni] = *(const bf16x8*)(buf + (offB[ni] ^ 64));
    }
    __builtin_amdgcn_s_setprio(1);
#pragma unroll
    for (int mi = 0; mi < 8; ++mi)
#pragma unroll
      for (int ni = 0; ni < 4; ++ni)
        acc[mi][ni] = __builtin_amdgcn_mfma_f32_16x16x32_bf16(
            a0[mi], b0r[ni], acc[mi][ni], 0, 0, 0);
#pragma unroll
    for (int mi = 0; mi < 8; ++mi)
#pragma unroll
      for (int ni = 0; ni < 4; ++ni)
        acc[mi][ni] = __builtin_amdgcn_mfma_f32_16x16x32_bf16(
            a1[mi], b1r[ni], acc[mi][ni], 0, 0, 0);
    __builtin_amdgcn_s_setprio(0);
  }

  // epilogue: C/D layout col=r16, row=g*4+q; fuse +bl (f32, pre-quantize)
  const int lf = bn >> 10;                       // leaf index 0..63
  float blv[4];
#pragma unroll
  for (int ni = 0; ni < 4; ++ni)
    blv[ni] = blg[(size_t)lf * ND + (bn & 1023) + wn * 64 + ni * 16 + r16];
#pragma unroll
  for (int mi = 0; mi < 8; ++mi)
#pragma unroll
    for (int q = 0; q < 4; ++q) {
      const long long grow = bm + wm * 128 + mi * 16 + g * 4 + q;
#pragma unroll
      for (int ni = 0; ni < 4; ++ni) {
        const int gcol = bn + wn * 64 + ni * 16 + r16;
        C[grow * ldc + gcol] = (_Float16)(acc[mi][ni][q] + blv[ni]);
      }
    }
}

// ------- kernel 4: softmax + weighted reduce, 1 wave per batch row -------
__global__ void __launch_bounds__(256) smax_kernel(
    const _Float16* __restrict__ Cg, const float* __restrict__ rt,
    float* __restrict__ out, int lpg, int l0, int first) {
  const int tid = threadIdx.x;
  const int wv = tid >> 6, ln = tid & 63;
  const int b = blockIdx.x * 4 + wv;
  const long long ldc = (long long)lpg * ND;
  const _Float16* base = Cg + (size_t)b * ldc + ln * 8;
  const float rtv = (ln < lpg) ? rt[(size_t)b * NLEAF + l0 + ln] : 0.f;

  float oacc[16];
#pragma unroll
  for (int k = 0; k < 16; ++k) oacc[k] = 0.f;

  for (int jj = 0; jj < lpg; ++jj) {
    const f16x8 h0 = *(const f16x8*)(base + jj * ND);
    const f16x8 h1 = *(const f16x8*)(base + jj * ND + 512);
    float e[16], s = 0.f;
#pragma unroll
    for (int k = 0; k < 8; ++k) { e[k] = __expf((float)h0[k]); s += e[k]; }
#pragma unroll
    for (int k = 0; k < 8; ++k) { e[8 + k] = __expf((float)h1[k]); s += e[8 + k]; }
#pragma unroll
    for (int off = 1; off < 64; off <<= 1) s += __shfl_xor(s, off);
    const float coef = __shfl(rtv, jj) / s;
#pragma unroll
    for (int k = 0; k < 16; ++k) oacc[k] += coef * e[k];
  }

  float* o0 = out + (size_t)b * ND + ln * 8;
  if (first) {
    *(float4*)o0         = (float4){oacc[0], oacc[1], oacc[2], oacc[3]};
    *(float4*)(o0 + 4)   = (float4){oacc[4], oacc[5], oacc[6], oacc[7]};
    *(float4*)(o0 + 512) = (float4){oacc[8], oacc[9], oacc[10], oacc[11]};
    *(float4*)(o0 + 516) = (float4){oacc[12], oacc[13], oacc[14], oacc[15]};
  } else {
#pragma unroll
    for (int part = 0; part < 4; ++part) {
      float* p = o0 + (part >> 1) * 512 + (part & 1) * 4;
      float4 v = *(const float4*)p;
      v.x += oacc[part * 4 + 0]; v.y += oacc[part * 4 + 1];
      v.z += oacc[part * 4 + 2]; v.w += oacc[part * 4 + 3];
      *(float4*)p = v;
    }
  }
}

extern "C" void kernel_launch(void* const* d_in, const int* in_sizes, int n_in,
                              void* d_out, int out_size, void* d_ws, size_t ws_size,
                              hipStream_t stream) {
  const float* x  = (const float*)d_in[0];
  const float* Wd = (const float*)d_in[1];
  const float* bd = (const float*)d_in[2];
  const float* Wl = (const float*)d_in[3];
  const float* bl = (const float*)d_in[4];
  float* out = (float*)d_out;
  char* ws = (char*)d_ws;
  unsigned short* wlb = (unsigned short*)(ws + WLB_OFF);
  unsigned short* xb  = (unsigned short*)(ws + XB_OFF);
  float* rt           = (float*)(ws + RT_OFF);
  _Float16* lg        = (_Float16*)(ws + LG_OFF);

  prep_kernel<<<RT_BLOCKS + 2048, 256, 0, stream>>>(Wl, x, Wd, bd, wlb, xb, rt);
  hipFuncSetAttribute((const void*)gemm_kernel,
                      hipFuncAttributeMaxDynamicSharedMemorySize, 131072);

  const int ntile = NLEAF * (ND / BN);           // 256 n-tiles, full 65536 cols
  gemm_kernel<<<8 * ntile, 512, 131072, stream>>>(xb, wlb, bl, lg, ntile);
  smax_kernel<<<BATCH / 4, 256, 0, stream>>>(lg, rt, out, NLEAF, 0, 1);
}

// Round 20
// 460.662 us; speedup vs baseline: 1.0485x; 1.0485x over previous
//
#include <hip/hip_runtime.h>
#include <hip/hip_bf16.h>

#define BATCH 2048
#define KD 1024
#define ND 1024
#define NLEAF 64
#define NGRP 2
#define LPG 32
#define BM 256
#define BN 256
// 16 K-tiles of BK=64

typedef __attribute__((ext_vector_type(8))) short bf16x8;
typedef __attribute__((ext_vector_type(4))) float f32x4;
typedef __attribute__((ext_vector_type(8))) _Float16 f16x8;

// workspace layout (bytes)
#define WLB_OFF 0ULL                 // B (Wl) bf16 row-major, 128 MB
#define XB_OFF  134217728ULL         // A (x) bf16 row-major, 4 MB
#define RT_OFF  138412032ULL         // routing 512 KB
#define LG_OFF  138936320ULL         // logits fp16 chunk, 128 MB (L3-resident)

__device__ __forceinline__ unsigned short f2bf(float f) {
  unsigned int u = __float_as_uint(f);
  u += 0x7fffu + ((u >> 16) & 1u);
  return (unsigned short)(u >> 16);
}

__device__ __forceinline__ void gload_lds16(const void* g, void* l) {
  __builtin_amdgcn_global_load_lds(
      (const __attribute__((address_space(1))) unsigned int*)g,
      (__attribute__((address_space(3))) unsigned int*)l, 16, 0, 0);
}

// ---------------- kernel 1: f32 -> bf16 conversion of Wl and x ----------------
__global__ void __launch_bounds__(256) convert_kernel(
    const float* __restrict__ Wl, const float* __restrict__ x,
    unsigned short* __restrict__ wlb, unsigned short* __restrict__ xb) {
  const long long WL4 = 16777216LL;
  const long long X4  = 524288LL;
  long long i = (long long)blockIdx.x * 256 + threadIdx.x;
  const long long stride = (long long)gridDim.x * 256;
  for (; i < WL4 + X4; i += stride) {
    float4 v;
    if (i < WL4) v = ((const float4*)Wl)[i];
    else         v = ((const float4*)x)[i - WL4];
    ushort4 o;
    o.x = f2bf(v.x); o.y = f2bf(v.y); o.z = f2bf(v.z); o.w = f2bf(v.w);
    if (i < WL4) ((ushort4*)wlb)[i] = o;
    else         ((ushort4*)xb)[i - WL4] = o;
  }
}

// ---------------- kernel 2: routing probabilities (f32 exact) ----------------
__global__ void __launch_bounds__(256) routing_kernel(
    const float* __restrict__ x, const float* __restrict__ Wd,
    const float* __restrict__ bd, float* __restrict__ rt) {
  __shared__ float xs[4][KD];
  __shared__ float sdp[4][64];
  const int tid = threadIdx.x;
  const int b0 = blockIdx.x * 4;
  const float4* xsrc = (const float4*)(x + (size_t)b0 * KD);
  float4* xdst = (float4*)&xs[0][0];
  for (int i = tid; i < KD; i += 256) xdst[i] = xsrc[i];
  __syncthreads();
  const int wv = tid >> 6, ln = tid & 63;
  const int b = b0 + wv;
  if (ln < 63) {
    const float4* wrow = (const float4*)(Wd + (size_t)ln * KD);
    const float4* xr = (const float4*)&xs[wv][0];
    float4 a = {0.f, 0.f, 0.f, 0.f};
    for (int k = 0; k < KD / 4; ++k) {
      float4 w = wrow[k], xv = xr[k];
      a.x += w.x * xv.x; a.y += w.y * xv.y; a.z += w.z * xv.z; a.w += w.w * xv.w;
    }
    float z = a.x + a.y + a.z + a.w + bd[ln];
    sdp[wv][ln] = 1.f / (1.f + __expf(-z));
  }
  __syncthreads();
  float prod = 1.f;
  int node = 0, index = ln;
  for (int d = 0; d < 6; ++d) {
    float pv = sdp[wv][node];
    prod *= (index & 1) ? (1.f - pv) : pv;
    node = node * 2 + 1 + (index & 1);
    index >>= 1;
  }
  rt[(size_t)b * NLEAF + ln] = prod;
}

// ---- kernel 3: 256x256 bf16 GEMM, BK=64, 2x64KB slots, ONE barrier+vmcnt ----
// ---- per tile; 24 upfront ds_reads overlap into 64 MFMAs (round-14 best) ----
__global__ void __launch_bounds__(512, 2) gemm_kernel(
    const unsigned short* __restrict__ A, const unsigned short* __restrict__ B,
    const float* __restrict__ blg, _Float16* __restrict__ C, int ntile) {
  extern __shared__ char smem[];   // 2 slots x 64KB: {A 32K | B 32K}
  const int tid = threadIdx.x;
  const int w = tid >> 6, ln = tid & 63;
  const int wm = w >> 2, wn = w & 3;
  const int g = ln >> 4, r16 = ln & 15;
  const int bid = blockIdx.x;
  const int j = bid >> 3;                       // XCD-chunked swizzle
  const int bm = (j & 7) * BM;
  const int bn = (((j >> 3) << 3) + (bid & 7)) * BN;
  const long long ldc = (long long)ntile * 256;

  // staging: rows 128B (8 chunks of 16B); thread -> (row tid>>3 + p*64, chunk tid&7)
  const int sr = tid >> 3, sj = tid & 7;
  const int sjx = sj ^ (sr & 7);                // both-sides swizzle, source
  const unsigned short* gA = A + (size_t)(bm + sr) * KD + sjx * 8;
  const unsigned short* gB = B + (size_t)(bn + sr) * KD + sjx * 8;
  const int ldsw = w * 1024;                    // wave-uniform dest component

  auto STAGE = [&](int t) {       // tile t (64 K-elems) -> slot t&1
    char* base = smem + (t & 1) * 65536;
    const size_t ko = (size_t)t * 64;
#pragma unroll
    for (int p = 0; p < 4; ++p) {
      gload_lds16(gA + (size_t)(p * 64) * KD + ko, base + p * 8192 + ldsw);
      gload_lds16(gB + (size_t)(p * 64) * KD + ko, base + 32768 + p * 8192 + ldsw);
    }
  };

  // read offsets: LDS chunk c holds source chunk c^(row&7); kk1 chunk 4^g -> ^64
  int offA[8], offB[4];
#pragma unroll
  for (int mi = 0; mi < 8; ++mi) {
    const int row = wm * 128 + mi * 16 + r16;
    offA[mi] = row * 128 + ((g ^ (row & 7)) * 16);
  }
#pragma unroll
  for (int ni = 0; ni < 4; ++ni) {
    const int row = wn * 64 + ni * 16 + r16;
    offB[ni] = 32768 + row * 128 + ((g ^ (row & 7)) * 16);
  }

  f32x4 acc[8][4];
#pragma unroll
  for (int mi = 0; mi < 8; ++mi)
#pragma unroll
    for (int ni = 0; ni < 4; ++ni) acc[mi][ni] = (f32x4){0.f, 0.f, 0.f, 0.f};

  STAGE(0);

  for (int t = 0; t < 16; ++t) {
    asm volatile("s_waitcnt vmcnt(0)" ::: "memory");   // STAGE(t) landed
    asm volatile("s_barrier" ::: "memory");            // slot t readable CU-wide;
                                                       // certifies reads(t-1) done
    if (t + 1 < 16) STAGE(t + 1);                      // slot (t+1)&1: tile t-1 done
    const char* buf = smem + (t & 1) * 65536;
    bf16x8 a0[8], a1[8], b0r[4], b1r[4];
#pragma unroll
    for (int mi = 0; mi < 8; ++mi) {
      a0[mi] = *(const bf16x8*)(buf + offA[mi]);
      a1[mi] = *(const bf16x8*)(buf + (offA[mi] ^ 64));
    }
#pragma unroll
    for (int ni = 0; ni < 4; ++ni) {
      b0r[ni] = *(const bf16x8*)(buf + offB[ni]);
      b1r[ni] = *(const bf16x8*)(buf + (offB[ni] ^ 64));
    }
    __builtin_amdgcn_s_setprio(1);
#pragma unroll
    for (int mi = 0; mi < 8; ++mi)
#pragma unroll
      for (int ni = 0; ni < 4; ++ni)
        acc[mi][ni] = __builtin_amdgcn_mfma_f32_16x16x32_bf16(
            a0[mi], b0r[ni], acc[mi][ni], 0, 0, 0);
#pragma unroll
    for (int mi = 0; mi < 8; ++mi)
#pragma unroll
      for (int ni = 0; ni < 4; ++ni)
        acc[mi][ni] = __builtin_amdgcn_mfma_f32_16x16x32_bf16(
            a1[mi], b1r[ni], acc[mi][ni], 0, 0, 0);
    __builtin_amdgcn_s_setprio(0);
  }

  // epilogue: C/D layout col=r16, row=g*4+q; fuse +bl (f32, pre-quantize)
  const int lf = bn >> 10;                       // leaf within this group
  float blv[4];
#pragma unroll
  for (int ni = 0; ni < 4; ++ni)
    blv[ni] = blg[(size_t)lf * ND + (bn & 1023) + wn * 64 + ni * 16 + r16];
#pragma unroll
  for (int mi = 0; mi < 8; ++mi)
#pragma unroll
    for (int q = 0; q < 4; ++q) {
      const long long grow = bm + wm * 128 + mi * 16 + g * 4 + q;
#pragma unroll
      for (int ni = 0; ni < 4; ++ni) {
        const int gcol = bn + wn * 64 + ni * 16 + r16;
        C[grow * ldc + gcol] = (_Float16)(acc[mi][ni][q] + blv[ni]);
      }
    }
}

// ------- kernel 4: softmax + weighted reduce, 1 wave per batch row -------
__global__ void __launch_bounds__(256) smax_kernel(
    const _Float16* __restrict__ Cg, const float* __restrict__ rt,
    float* __restrict__ out, int lpg, int l0, int first) {
  const int tid = threadIdx.x;
  const int wv = tid >> 6, ln = tid & 63;
  const int b = blockIdx.x * 4 + wv;
  const long long ldc = (long long)lpg * ND;
  const _Float16* base = Cg + (size_t)b * ldc + ln * 8;
  const float rtv = (ln < lpg) ? rt[(size_t)b * NLEAF + l0 + ln] : 0.f;

  float oacc[16];
#pragma unroll
  for (int k = 0; k < 16; ++k) oacc[k] = 0.f;

  for (int jj = 0; jj < lpg; ++jj) {
    const f16x8 h0 = *(const f16x8*)(base + jj * ND);
    const f16x8 h1 = *(const f16x8*)(base + jj * ND + 512);
    float e[16], s = 0.f;
#pragma unroll
    for (int k = 0; k < 8; ++k) { e[k] = __expf((float)h0[k]); s += e[k]; }
#pragma unroll
    for (int k = 0; k < 8; ++k) { e[8 + k] = __expf((float)h1[k]); s += e[8 + k]; }
#pragma unroll
    for (int off = 1; off < 64; off <<= 1) s += __shfl_xor(s, off);
    const float coef = __shfl(rtv, jj) / s;
#pragma unroll
    for (int k = 0; k < 16; ++k) oacc[k] += coef * e[k];
  }

  float* o0 = out + (size_t)b * ND + ln * 8;
  if (first) {
    *(float4*)o0         = (float4){oacc[0], oacc[1], oacc[2], oacc[3]};
    *(float4*)(o0 + 4)   = (float4){oacc[4], oacc[5], oacc[6], oacc[7]};
    *(float4*)(o0 + 512) = (float4){oacc[8], oacc[9], oacc[10], oacc[11]};
    *(float4*)(o0 + 516) = (float4){oacc[12], oacc[13], oacc[14], oacc[15]};
  } else {
#pragma unroll
    for (int part = 0; part < 4; ++part) {
      float* p = o0 + (part >> 1) * 512 + (part & 1) * 4;
      float4 v = *(const float4*)p;
      v.x += oacc[part * 4 + 0]; v.y += oacc[part * 4 + 1];
      v.z += oacc[part * 4 + 2]; v.w += oacc[part * 4 + 3];
      *(float4*)p = v;
    }
  }
}

extern "C" void kernel_launch(void* const* d_in, const int* in_sizes, int n_in,
                              void* d_out, int out_size, void* d_ws, size_t ws_size,
                              hipStream_t stream) {
  const float* x  = (const float*)d_in[0];
  const float* Wd = (const float*)d_in[1];
  const float* bd = (const float*)d_in[2];
  const float* Wl = (const float*)d_in[3];
  const float* bl = (const float*)d_in[4];
  float* out = (float*)d_out;
  char* ws = (char*)d_ws;
  unsigned short* wlb = (unsigned short*)(ws + WLB_OFF);
  unsigned short* xb  = (unsigned short*)(ws + XB_OFF);
  float* rt           = (float*)(ws + RT_OFF);
  _Float16* lg        = (_Float16*)(ws + LG_OFF);

  convert_kernel<<<2048, 256, 0, stream>>>(Wl, x, wlb, xb);
  routing_kernel<<<BATCH / 4, 256, 0, stream>>>(x, Wd, bd, rt);
  hipFuncSetAttribute((const void*)gemm_kernel,
                      hipFuncAttributeMaxDynamicSharedMemorySize, 131072);

  const int ntile = LPG * (ND / BN);             // 128 n-tiles per chunk
  for (int grp = 0; grp < NGRP; ++grp) {
    gemm_kernel<<<8 * ntile, 512, 131072, stream>>>(
        xb, wlb + (size_t)grp * LPG * ND * KD,
        bl + (size_t)grp * LPG * ND, lg, ntile);
    smax_kernel<<<BATCH / 4, 256, 0, stream>>>(lg, rt, out,
                                               LPG, grp * LPG, grp == 0);
  }
}